// Round 20
// baseline (197.703 us; speedup 1.0000x reference)
//
#include <hip/hip_runtime.h>

typedef __bf16 bf16;
typedef __bf16 bf16x4 __attribute__((ext_vector_type(4)));
typedef __bf16 bf16x8 __attribute__((ext_vector_type(8)));
typedef float f32x4 __attribute__((ext_vector_type(4)));
typedef float f32x16 __attribute__((ext_vector_type(16)));
typedef unsigned u32x2 __attribute__((ext_vector_type(2)));

static constexpr int NB = 4;       // batch
static constexpr int NS = 2048;    // seq
static constexpr int ND = 1024;    // model dim
static constexpr int NH = 16;      // heads
static constexpr int HD = 64;      // head dim
static constexpr float QSCALE = 0.18033688011112042f;  // log2(e)/sqrt(64)

// async global->LDS, 16B per lane; LDS dest = wave-uniform base + lane*16
#define GL16(g, l)                                                             \
    __builtin_amdgcn_global_load_lds(                                          \
        (const __attribute__((address_space(1))) void*)(g),                    \
        (__attribute__((address_space(3))) void*)(l), 16, 0, 0)

static __device__ __forceinline__ unsigned pk2(float a, float b) {
    union { __bf16 h[2]; unsigned u; } t;
    t.h[0] = (__bf16)a; t.h[1] = (__bf16)b;
    return t.u;
}

// ---------------- convert f32 -> bf16 (vectorized) ----------------
__global__ void k_conv(const float* __restrict__ in, bf16* __restrict__ out, int n) {
    int i = (blockIdx.x * blockDim.x + threadIdx.x) * 4;
    if (i < n) {
        float4 v = *reinterpret_cast<const float4*>(in + i);
        bf16* o = out + i;
        o[0] = (bf16)v.x; o[1] = (bf16)v.y; o[2] = (bf16)v.z; o[3] = (bf16)v.w;
    }
}

// ------- transpose + convert: in[K][N] f32 -> out[N][K] bf16, full-line out ---
__global__ void k_transconv(const float* __restrict__ in, bf16* __restrict__ out,
                            int K, int N) {
    __shared__ float tile[64][33];
    int k0 = blockIdx.y * 64, n0 = blockIdx.x * 32;
    int tx = threadIdx.x, ty = threadIdx.y;  // block (32,8)
#pragma unroll
    for (int i = 0; i < 8; ++i)
        tile[ty + 8 * i][tx] = in[(long)(k0 + ty + 8 * i) * N + n0 + tx];
    __syncthreads();
    int t = ty * 32 + tx;
    int row = t >> 3;            // n-local 0..31
    int col8 = (t & 7) * 8;      // k-local chunk
    bf16x8 v;
#pragma unroll
    for (int c = 0; c < 8; ++c) v[c] = (bf16)tile[col8 + c][row];
    *reinterpret_cast<bf16x8*>(&out[(long)(n0 + row) * K + k0 + col8]) = v;
}

// ======== merged QKV GEMM, 128x128, 2-phase + counted vmcnt ==================
// All blocks: swapped mfma (lane holds s-row fixed, 4 consecutive n-cols).
// Q/K blocks (cols<2048): full-line [s][hd] store (Q scaled).
// V blocks  (cols>=2048): straight gather-transpose from eb, full-line [d][s].
__global__ __launch_bounds__(256, 2) void k_gemmQKV(
    const bf16* __restrict__ A, const bf16* __restrict__ Bt,
    const float* __restrict__ bias,
    bf16* __restrict__ Qb, bf16* __restrict__ Kb, bf16* __restrict__ Vt,
    int Kd)
{
    constexpr int BM = 128, BN = 128, BK = 64;
    __shared__ __align__(16) bf16 As[2][BM * BK];
    __shared__ __align__(16) bf16 Bs[2][BN * BK];

    const int t = threadIdx.x;
    const int wid = t >> 6, lane = t & 63;
    const int wm = wid >> 1, wn = wid & 1;
    const int m0 = blockIdx.y * BM, n0 = blockIdx.x * BN;
    const int lrow = lane & 15, lhi = lane >> 4;

    const int srow0 = wid * 32 + (lane >> 3);
    const int scol = ((lane & 7) ^ (lane >> 3)) * 8;
    const bf16* ag = A + (long)(m0 + srow0) * Kd + scol;
    const bf16* bg = Bt + (long)(n0 + srow0) * Kd + scol;

    auto STAGE = [&](int buf_, int k0_) {
#pragma unroll
        for (int c = 0; c < 4; ++c) {
            GL16(ag + (long)(c * 8) * Kd + k0_, &As[buf_][(wid * 32 + c * 8) * BK]);
            GL16(bg + (long)(c * 8) * Kd + k0_, &Bs[buf_][(wid * 32 + c * 8) * BK]);
        }
    };

    f32x4 acc[4][4] = {};
    const int nt = Kd >> 6;
    const int swzr = (lrow & 7) << 4;
    int co[2];
#pragma unroll
    for (int kk = 0; kk < 2; ++kk)
        co[kk] = ((kk * 64 + lhi * 16) ^ swzr) >> 1;

    STAGE(0, 0);
    int cur = 0;
    for (int tix = 0; tix < nt; ++tix) {
        if (tix + 1 < nt) {
            STAGE(cur ^ 1, (tix + 1) * BK);
            asm volatile("s_waitcnt vmcnt(8)" ::: "memory");
        } else {
            asm volatile("s_waitcnt vmcnt(0)" ::: "memory");
        }
        __builtin_amdgcn_s_barrier();
        __builtin_amdgcn_sched_barrier(0);

        bf16x8 af[2][4], bfr[2][4];
#pragma unroll
        for (int kk = 0; kk < 2; ++kk)
#pragma unroll
            for (int i = 0; i < 4; ++i) {
                af[kk][i]  = *reinterpret_cast<const bf16x8*>(
                    &As[cur][(wm * 64 + i * 16 + lrow) * BK + co[kk]]);
                bfr[kk][i] = *reinterpret_cast<const bf16x8*>(
                    &Bs[cur][(wn * 64 + i * 16 + lrow) * BK + co[kk]]);
            }
        __builtin_amdgcn_s_setprio(1);
#pragma unroll
        for (int kk = 0; kk < 2; ++kk)
#pragma unroll
            for (int i = 0; i < 4; ++i)
#pragma unroll
                for (int j = 0; j < 4; ++j)
                    acc[i][j] = __builtin_amdgcn_mfma_f32_16x16x32_bf16(
                        bfr[kk][j], af[kk][i], acc[i][j], 0, 0, 0);
        __builtin_amdgcn_s_setprio(0);
        __builtin_amdgcn_s_barrier();   // also covers epilogue LDS reuse
        cur ^= 1;
    }

    const int colbase = n0 + wn * 64;
    const int which = colbase >> 10;          // 0:Q 1:K 2:V
    const bool isQ = (which == 0);

    // common eb-write: wave-private 64(s) x 64(n) swizzled tile
    bf16* eb = (bf16*)As + wid * 4096;
#pragma unroll
    for (int j = 0; j < 4; ++j) {
        f32x4 bv = *reinterpret_cast<const f32x4*>(&bias[colbase + j * 16 + 4 * lhi]);
#pragma unroll
        for (int i = 0; i < 4; ++i) {
            int srt = i * 16 + lrow;
            bf16x4 pk;
#pragma unroll
            for (int r = 0; r < 4; ++r) {
                float v = acc[i][j][r] + bv[r];
                pk[r] = (bf16)(isQ ? v * QSCALE : v);
            }
            *reinterpret_cast<bf16x4*>(
                reinterpret_cast<char*>(eb) + srt * 128 +
                (((j * 16 + 4 * lhi) * 2) ^ ((srt & 7) << 4))) = pk;
        }
    }
    const int h = (colbase & 1023) >> 6;
    const int mrow = m0 + wm * 64;
    const int bb = mrow >> 11, s0 = mrow & 2047;
    const long bh = (long)bb * NH + h;

    if (which < 2) {
        bf16* Ob = isQ ? Qb : Kb;
#pragma unroll
        for (int it = 0; it < 8; ++it) {
            int rt = it * 8 + (lane >> 3);
            bf16x8 v = *reinterpret_cast<const bf16x8*>(
                reinterpret_cast<char*>(eb) + rt * 128 +
                (((lane & 7) * 16) ^ ((rt & 7) << 4)));
            int s = s0 + rt;
            *reinterpret_cast<bf16x8*>(&Ob[(bh * NS + s) * HD + (lane & 7) * 8]) = v;
        }
    } else {
        // V: straight gather-transpose, full-line [d][s] store
        const int pos0 = (lane & 7) * 8;
#pragma unroll
        for (int it = 0; it < 8; ++it) {
            int dt = it * 8 + (lane >> 3);
            bf16x8 v;
#pragma unroll
            for (int j = 0; j < 8; ++j) {
                int s = pos0 + j;   // source s-row in eb
                v[j] = *reinterpret_cast<const bf16*>(
                    reinterpret_cast<char*>(eb) + s * 128 +
                    ((dt * 2) ^ ((s & 7) << 4)));
            }
            *reinterpret_cast<bf16x8*>(&Vt[(bh * HD + dt) * NS + s0 + pos0]) = v;
        }
    }
}

// ======== out-GEMM, 128x128, 2-phase + counted vmcnt, f32 full-line out ======
__global__ __launch_bounds__(256, 2) void k_gemmO(
    const bf16* __restrict__ A, const bf16* __restrict__ Bt,
    const float* __restrict__ bias, float* __restrict__ O, int Kd)
{
    constexpr int BM = 128, BN = 128, BK = 64;
    __shared__ __align__(16) bf16 As[2][BM * BK];
    __shared__ __align__(16) bf16 Bs[2][BN * BK];

    const int t = threadIdx.x;
    const int wid = t >> 6, lane = t & 63;
    const int wm = wid >> 1, wn = wid & 1;
    const int m0 = blockIdx.y * BM, n0 = blockIdx.x * BN;
    const int lrow = lane & 15, lhi = lane >> 4;

    const int srow0 = wid * 32 + (lane >> 3);
    const int scol = ((lane & 7) ^ (lane >> 3)) * 8;
    const bf16* ag = A + (long)(m0 + srow0) * Kd + scol;
    const bf16* bg = Bt + (long)(n0 + srow0) * Kd + scol;

    auto STAGE = [&](int buf_, int k0_) {
#pragma unroll
        for (int c = 0; c < 4; ++c) {
            GL16(ag + (long)(c * 8) * Kd + k0_, &As[buf_][(wid * 32 + c * 8) * BK]);
            GL16(bg + (long)(c * 8) * Kd + k0_, &Bs[buf_][(wid * 32 + c * 8) * BK]);
        }
    };

    f32x4 acc[4][4] = {};
    const int nt = Kd >> 6;
    const int swzr = (lrow & 7) << 4;
    int co[2];
#pragma unroll
    for (int kk = 0; kk < 2; ++kk)
        co[kk] = ((kk * 64 + lhi * 16) ^ swzr) >> 1;

    STAGE(0, 0);
    int cur = 0;
    for (int tix = 0; tix < nt; ++tix) {
        if (tix + 1 < nt) {
            STAGE(cur ^ 1, (tix + 1) * BK);
            asm volatile("s_waitcnt vmcnt(8)" ::: "memory");
        } else {
            asm volatile("s_waitcnt vmcnt(0)" ::: "memory");
        }
        __builtin_amdgcn_s_barrier();
        __builtin_amdgcn_sched_barrier(0);

        bf16x8 af[2][4], bfr[2][4];
#pragma unroll
        for (int kk = 0; kk < 2; ++kk)
#pragma unroll
            for (int i = 0; i < 4; ++i) {
                af[kk][i]  = *reinterpret_cast<const bf16x8*>(
                    &As[cur][(wm * 64 + i * 16 + lrow) * BK + co[kk]]);
                bfr[kk][i] = *reinterpret_cast<const bf16x8*>(
                    &Bs[cur][(wn * 64 + i * 16 + lrow) * BK + co[kk]]);
            }
        __builtin_amdgcn_s_setprio(1);
#pragma unroll
        for (int kk = 0; kk < 2; ++kk)
#pragma unroll
            for (int i = 0; i < 4; ++i)
#pragma unroll
                for (int j = 0; j < 4; ++j)
                    acc[i][j] = __builtin_amdgcn_mfma_f32_16x16x32_bf16(
                        bfr[kk][j], af[kk][i], acc[i][j], 0, 0, 0);
        __builtin_amdgcn_s_setprio(0);
        __builtin_amdgcn_s_barrier();
        cur ^= 1;
    }

    const int colbase = n0 + wn * 64;
    float* ef = (float*)As + wid * 2048;   // wave-private 32x64 f32 (8 KB)
#pragma unroll
    for (int half = 0; half < 2; ++half) {
#pragma unroll
        for (int i2 = 0; i2 < 2; ++i2) {
            int i = half * 2 + i2;
            int srt = i2 * 16 + lrow;
#pragma unroll
            for (int j = 0; j < 4; ++j) {
                f32x4 bv = *reinterpret_cast<const f32x4*>(
                    &bias[colbase + j * 16 + 4 * lhi]);
                f32x4 v = acc[i][j] + bv;
                *reinterpret_cast<f32x4*>(
                    reinterpret_cast<char*>(ef) + srt * 256 +
                    (((j * 16 + 4 * lhi) * 4) ^ ((srt & 7) << 4))) = v;
            }
        }
#pragma unroll
        for (int it = 0; it < 8; ++it) {
            int rt = it * 4 + (lane >> 4);
            f32x4 v = *reinterpret_cast<const f32x4*>(
                reinterpret_cast<char*>(ef) + rt * 256 +
                (((lane & 15) * 16) ^ ((rt & 7) << 4)));
            int row = m0 + wm * 64 + half * 32 + rt;
            *reinterpret_cast<f32x4*>(
                &O[(long)row * 1024 + colbase + (lane & 15) * 4]) = v;
        }
        asm volatile("" ::: "memory");   // half0 reads before half1 writes
    }
}

// ---------------- flash attention v12: 32x32 datapath, 4-wave blocks ---------
// 4 waves, 128 q/block, 32 q/wave, grid 1024 -> 4 independent blocks/CU
// (decorrelated phases: one block's softmax overlaps another's MFMA).
// Same datapath as v11. LDS 32 KB/block. Counted vmcnt(4) staging.
__global__ __launch_bounds__(256, 4) void k_attn(
    const bf16* __restrict__ Qb, const bf16* __restrict__ Kb,
    const bf16* __restrict__ Vt, bf16* __restrict__ Ao)
{
    constexpr int KB = 64;
    constexpr int NT = NS / KB;   // 32 tiles
    __shared__ __align__(16) bf16 Ks[2][KB * HD];   // 16 KB, row=key, swizzled
    __shared__ __align__(16) bf16 Vs[2][HD * KB];   // 16 KB, row=d,   swizzled

    const int t = threadIdx.x;
    const int wid = t >> 6, lane = t & 63;
    const int l31 = lane & 31, lh = lane >> 5;      // 32-lane row, half-select

    // bijective XCD swizzle: 1024 blocks, 8 XCDs, 128 contiguous per XCD
    const int flat = blockIdx.y * gridDim.x + blockIdx.x;
    const int n = (flat & 7) * 128 + (flat >> 3);
    const int bh = n >> 4;
    const int qw = (n & 15) * 128 + wid * 32;   // wave's 32 q rows

    const bf16* Qg = Qb + ((long)bh * NS + qw) * HD;
    const bf16* Kg = Kb + (long)bh * NS * HD;
    const bf16* Vg = Vt + (long)bh * HD * NS;

    // Q fragments (B-operand, 32x32x16): col=q=l31, k(d) = kc*16 + 8*lh + {0..7}
    bf16x8 qf[4];
#pragma unroll
    for (int kc = 0; kc < 4; ++kc)
        qf[kc] = *reinterpret_cast<const bf16x8*>(
            Qg + (long)l31 * HD + kc * 16 + 8 * lh);

    f32x16 of0 = {}, of1 = {};
    float lsum = 0.f;

    // staging: wave w covers K rows w*16..+16 and V rows w*16..+16 (4 GL16)
    const int gsr = lane >> 3;
    const int gsc = ((lane & 7) ^ gsr) * 8;
    const int rb = wid * 16;
    auto STAGE = [&](int buf, int kb) {
        GL16(Kg + (long)(kb + rb + gsr) * HD + gsc,     &Ks[buf][rb * 64]);
        GL16(Kg + (long)(kb + rb + 8 + gsr) * HD + gsc, &Ks[buf][(rb + 8) * 64]);
        GL16(Vg + (long)(rb + gsr) * NS + kb + gsc,     &Vs[buf][rb * 64]);
        GL16(Vg + (long)(rb + 8 + gsr) * NS + kb + gsc, &Vs[buf][(rb + 8) * 64]);
    };

    auto COMPUTE = [&](int b_) {
        // QK: st[kt] = sum_kc mfma32x32x16(K[kt][kc], qf[kc])
        f32x16 st0 = {}, st1 = {};
        __builtin_amdgcn_s_setprio(1);
#pragma unroll
        for (int kc = 0; kc < 4; ++kc) {
            const int cb = (kc * 32 + 16 * lh);
            const int r0 = l31, r1 = 32 + l31;
            bf16x8 k0 = *reinterpret_cast<const bf16x8*>(
                &Ks[b_][r0 * 64 + ((cb ^ ((r0 & 7) << 4)) >> 1)]);
            bf16x8 k1 = *reinterpret_cast<const bf16x8*>(
                &Ks[b_][r1 * 64 + ((cb ^ ((r1 & 7) << 4)) >> 1)]);
            st0 = __builtin_amdgcn_mfma_f32_32x32x16_bf16(k0, qf[kc], st0, 0, 0, 0);
            st1 = __builtin_amdgcn_mfma_f32_32x32x16_bf16(k1, qf[kc], st1, 0, 0, 0);
        }
        __builtin_amdgcn_s_setprio(0);

        // softmax in-register; pack per group g: keys 8g + 4*lh + {0..3}
        unsigned u0[4][2], u1[4][2];
#pragma unroll
        for (int g = 0; g < 4; ++g) {
            float a0 = __builtin_amdgcn_exp2f(st0[4 * g]);
            float a1 = __builtin_amdgcn_exp2f(st0[4 * g + 1]);
            float a2 = __builtin_amdgcn_exp2f(st0[4 * g + 2]);
            float a3 = __builtin_amdgcn_exp2f(st0[4 * g + 3]);
            lsum += (a0 + a1) + (a2 + a3);
            u0[g][0] = pk2(a0, a1); u0[g][1] = pk2(a2, a3);
            float b0 = __builtin_amdgcn_exp2f(st1[4 * g]);
            float b1 = __builtin_amdgcn_exp2f(st1[4 * g + 1]);
            float b2 = __builtin_amdgcn_exp2f(st1[4 * g + 2]);
            float b3 = __builtin_amdgcn_exp2f(st1[4 * g + 3]);
            lsum += (b0 + b1) + (b2 + b3);
            u1[g][0] = pk2(b0, b1); u1[g][1] = pk2(b2, b3);
        }

        // PV: for global key-chunk kc: B-frag via 2 permlane32_swap; 2 d-tiles
        __builtin_amdgcn_s_setprio(1);
#pragma unroll
        for (int kc = 0; kc < 4; ++kc) {
            const unsigned (*uu)[2] = (kc < 2) ? u0 : u1;
            const int gl = 2 * (kc & 1), gh = gl + 1;
            u32x2 sA = __builtin_amdgcn_permlane32_swap(uu[gl][0], uu[gh][0], false, false);
            u32x2 sB = __builtin_amdgcn_permlane32_swap(uu[gl][1], uu[gh][1], false, false);
            union { unsigned u[4]; bf16x8 v; } pf;
            pf.u[0] = sA[0]; pf.u[1] = sB[0]; pf.u[2] = sA[1]; pf.u[3] = sB[1];
            const int cb = kc * 32 + 16 * lh;
#pragma unroll
            for (int dt = 0; dt < 2; ++dt) {
                const int row = dt * 32 + l31;
                bf16x8 vf = *reinterpret_cast<const bf16x8*>(
                    &Vs[b_][row * 64 + ((cb ^ ((row & 7) << 4)) >> 1)]);
                if (dt == 0)
                    of0 = __builtin_amdgcn_mfma_f32_32x32x16_bf16(vf, pf.v, of0, 0, 0, 0);
                else
                    of1 = __builtin_amdgcn_mfma_f32_32x32x16_bf16(vf, pf.v, of1, 0, 0, 0);
            }
        }
        __builtin_amdgcn_s_setprio(0);
    };

    STAGE(0, 0);
    int cur = 0;
    for (int it = 0; it < NT; ++it) {
        if (it + 1 < NT) {
            STAGE(cur ^ 1, (it + 1) * KB);
            asm volatile("s_waitcnt vmcnt(4)" ::: "memory");  // cur's 4 landed
        } else {
            asm volatile("s_waitcnt vmcnt(0)" ::: "memory");
        }
        __builtin_amdgcn_s_barrier();
        __builtin_amdgcn_sched_barrier(0);
        COMPUTE(cur);
        __builtin_amdgcn_s_barrier();   // reads of cur done -> overwrite ok
        cur ^= 1;
    }

    // lanes l and l+32 hold the same q; combine their key-halves
    lsum += __shfl_xor(lsum, 32);
    const float inv = 1.0f / lsum;

    // epilogue: wave-private 32(q) x 64(d) transpose in Ks (4 waves x 4 KB)
    bf16* eb = (bf16*)Ks + wid * 2048;
    const int qrow = l31;
#pragma unroll
    for (int dt = 0; dt < 2; ++dt)
#pragma unroll
        for (int g = 0; g < 4; ++g) {
            bf16x4 pk;
#pragma unroll
            for (int r = 0; r < 4; ++r) {
                float v = (dt == 0) ? of0[4 * g + r] : of1[4 * g + r];
                pk[r] = (bf16)(v * inv);
            }
            int d = dt * 32 + 8 * g + 4 * lh;
            *reinterpret_cast<bf16x4*>(
                reinterpret_cast<char*>(eb) + qrow * 128 +
                ((d * 2) ^ ((qrow & 7) << 4))) = pk;
        }
    const int bb = bh >> 4, h = bh & 15;
#pragma unroll
    for (int it = 0; it < 4; ++it) {
        int rt = it * 8 + (lane >> 3);
        bf16x8 v = *reinterpret_cast<const bf16x8*>(
            reinterpret_cast<char*>(eb) + rt * 128 +
            (((lane & 7) * 16) ^ ((rt & 7) << 4)));
        int s = qw + rt;
        *reinterpret_cast<bf16x8*>(
            &Ao[((long)bb * NS + s) * ND + h * HD + (lane & 7) * 8]) = v;
    }
}

// ---------------- launch ----------------
extern "C" void kernel_launch(void* const* d_in, const int* in_sizes, int n_in,
                              void* d_out, int out_size, void* d_ws, size_t ws_size,
                              hipStream_t stream) {
    const float* x    = (const float*)d_in[0];
    const float* Wqkv = (const float*)d_in[1];
    const float* bqkv = (const float*)d_in[2];
    const float* Wout = (const float*)d_in[3];
    const float* bout = (const float*)d_in[4];
    float* out = (float*)d_out;

    char* ws = (char*)d_ws;
    bf16* Xb  = (bf16*)(ws);                         // 16.78 MB
    bf16* Wqt = (bf16*)(ws + 16777216);              //  6.29 MB
    bf16* Wot = (bf16*)(ws + 23068672);              //  2.10 MB
    bf16* Qb  = (bf16*)(ws + 25165824);              // 16.78 MB
    bf16* Kb  = (bf16*)(ws + 41943040);              // 16.78 MB
    bf16* Vt  = (bf16*)(ws + 58720256);              // 16.78 MB
    bf16* Ab  = (bf16*)(ws + 75497472);              // 16.78 MB  (total ~92 MB)

    k_conv<<<dim3(8192), dim3(256), 0, stream>>>(x, Xb, NB * NS * ND);
    k_transconv<<<dim3(96, 16), dim3(32, 8), 0, stream>>>(Wqkv, Wqt, ND, 3 * ND);
    k_transconv<<<dim3(32, 16), dim3(32, 8), 0, stream>>>(Wout, Wot, ND, ND);

    // merged QKV producer: 1536 blocks = 3 exact generations at 2/CU
    k_gemmQKV<<<dim3(24, 64), dim3(256), 0, stream>>>(
        Xb, Wqt, bqkv, Qb, Kb, Vt, ND);

    k_attn<<<dim3(16, 64), dim3(256), 0, stream>>>(Qb, Kb, Vt, Ab);

    k_gemmO<<<dim3(8, 64), dim3(256), 0, stream>>>(
        Ab, Wot, bout, out, ND);
}

// Round 21
// 192.388 us; speedup vs baseline: 1.0276x; 1.0276x over previous
//
#include <hip/hip_runtime.h>

typedef __bf16 bf16;
typedef __bf16 bf16x4 __attribute__((ext_vector_type(4)));
typedef __bf16 bf16x8 __attribute__((ext_vector_type(8)));
typedef float f32x4 __attribute__((ext_vector_type(4)));
typedef float f32x16 __attribute__((ext_vector_type(16)));
typedef unsigned u32x2 __attribute__((ext_vector_type(2)));

static constexpr int NB = 4;       // batch
static constexpr int NS = 2048;    // seq
static constexpr int ND = 1024;    // model dim
static constexpr int NH = 16;      // heads
static constexpr int HD = 64;      // head dim
static constexpr float QSCALE = 0.18033688011112042f;  // log2(e)/sqrt(64)

// async global->LDS, 16B per lane; LDS dest = wave-uniform base + lane*16
#define GL16(g, l)                                                             \
    __builtin_amdgcn_global_load_lds(                                          \
        (const __attribute__((address_space(1))) void*)(g),                    \
        (__attribute__((address_space(3))) void*)(l), 16, 0, 0)

static __device__ __forceinline__ unsigned pk2(float a, float b) {
    union { __bf16 h[2]; unsigned u; } t;
    t.h[0] = (__bf16)a; t.h[1] = (__bf16)b;
    return t.u;
}

// ---------------- convert f32 -> bf16 (vectorized) ----------------
__global__ void k_conv(const float* __restrict__ in, bf16* __restrict__ out, int n) {
    int i = (blockIdx.x * blockDim.x + threadIdx.x) * 4;
    if (i < n) {
        float4 v = *reinterpret_cast<const float4*>(in + i);
        bf16* o = out + i;
        o[0] = (bf16)v.x; o[1] = (bf16)v.y; o[2] = (bf16)v.z; o[3] = (bf16)v.w;
    }
}

// ------- transpose + convert: in[K][N] f32 -> out[N][K] bf16, full-line out ---
__global__ void k_transconv(const float* __restrict__ in, bf16* __restrict__ out,
                            int K, int N) {
    __shared__ float tile[64][33];
    int k0 = blockIdx.y * 64, n0 = blockIdx.x * 32;
    int tx = threadIdx.x, ty = threadIdx.y;  // block (32,8)
#pragma unroll
    for (int i = 0; i < 8; ++i)
        tile[ty + 8 * i][tx] = in[(long)(k0 + ty + 8 * i) * N + n0 + tx];
    __syncthreads();
    int t = ty * 32 + tx;
    int row = t >> 3;            // n-local 0..31
    int col8 = (t & 7) * 8;      // k-local chunk
    bf16x8 v;
#pragma unroll
    for (int c = 0; c < 8; ++c) v[c] = (bf16)tile[col8 + c][row];
    *reinterpret_cast<bf16x8*>(&out[(long)(n0 + row) * K + k0 + col8]) = v;
}

// ======== merged QKV GEMM, 128x128, 2-phase + counted vmcnt ==================
// All blocks: swapped mfma (lane holds s-row fixed, 4 consecutive n-cols).
// Q/K blocks (cols<2048): full-line [s][hd] store (Q scaled).
// V blocks  (cols>=2048): straight gather-transpose from eb, full-line [d][s].
__global__ __launch_bounds__(256, 2) void k_gemmQKV(
    const bf16* __restrict__ A, const bf16* __restrict__ Bt,
    const float* __restrict__ bias,
    bf16* __restrict__ Qb, bf16* __restrict__ Kb, bf16* __restrict__ Vt,
    int Kd)
{
    constexpr int BM = 128, BN = 128, BK = 64;
    __shared__ __align__(16) bf16 As[2][BM * BK];
    __shared__ __align__(16) bf16 Bs[2][BN * BK];

    const int t = threadIdx.x;
    const int wid = t >> 6, lane = t & 63;
    const int wm = wid >> 1, wn = wid & 1;
    const int m0 = blockIdx.y * BM, n0 = blockIdx.x * BN;
    const int lrow = lane & 15, lhi = lane >> 4;

    const int srow0 = wid * 32 + (lane >> 3);
    const int scol = ((lane & 7) ^ (lane >> 3)) * 8;
    const bf16* ag = A + (long)(m0 + srow0) * Kd + scol;
    const bf16* bg = Bt + (long)(n0 + srow0) * Kd + scol;

    auto STAGE = [&](int buf_, int k0_) {
#pragma unroll
        for (int c = 0; c < 4; ++c) {
            GL16(ag + (long)(c * 8) * Kd + k0_, &As[buf_][(wid * 32 + c * 8) * BK]);
            GL16(bg + (long)(c * 8) * Kd + k0_, &Bs[buf_][(wid * 32 + c * 8) * BK]);
        }
    };

    f32x4 acc[4][4] = {};
    const int nt = Kd >> 6;
    const int swzr = (lrow & 7) << 4;
    int co[2];
#pragma unroll
    for (int kk = 0; kk < 2; ++kk)
        co[kk] = ((kk * 64 + lhi * 16) ^ swzr) >> 1;

    STAGE(0, 0);
    int cur = 0;
    for (int tix = 0; tix < nt; ++tix) {
        if (tix + 1 < nt) {
            STAGE(cur ^ 1, (tix + 1) * BK);
            asm volatile("s_waitcnt vmcnt(8)" ::: "memory");
        } else {
            asm volatile("s_waitcnt vmcnt(0)" ::: "memory");
        }
        __builtin_amdgcn_s_barrier();
        __builtin_amdgcn_sched_barrier(0);

        bf16x8 af[2][4], bfr[2][4];
#pragma unroll
        for (int kk = 0; kk < 2; ++kk)
#pragma unroll
            for (int i = 0; i < 4; ++i) {
                af[kk][i]  = *reinterpret_cast<const bf16x8*>(
                    &As[cur][(wm * 64 + i * 16 + lrow) * BK + co[kk]]);
                bfr[kk][i] = *reinterpret_cast<const bf16x8*>(
                    &Bs[cur][(wn * 64 + i * 16 + lrow) * BK + co[kk]]);
            }
        __builtin_amdgcn_s_setprio(1);
#pragma unroll
        for (int kk = 0; kk < 2; ++kk)
#pragma unroll
            for (int i = 0; i < 4; ++i)
#pragma unroll
                for (int j = 0; j < 4; ++j)
                    acc[i][j] = __builtin_amdgcn_mfma_f32_16x16x32_bf16(
                        bfr[kk][j], af[kk][i], acc[i][j], 0, 0, 0);
        __builtin_amdgcn_s_setprio(0);
        __builtin_amdgcn_s_barrier();   // also covers epilogue LDS reuse
        cur ^= 1;
    }

    const int colbase = n0 + wn * 64;
    const int which = colbase >> 10;          // 0:Q 1:K 2:V
    const bool isQ = (which == 0);

    // common eb-write: wave-private 64(s) x 64(n) swizzled tile
    bf16* eb = (bf16*)As + wid * 4096;
#pragma unroll
    for (int j = 0; j < 4; ++j) {
        f32x4 bv = *reinterpret_cast<const f32x4*>(&bias[colbase + j * 16 + 4 * lhi]);
#pragma unroll
        for (int i = 0; i < 4; ++i) {
            int srt = i * 16 + lrow;
            bf16x4 pk;
#pragma unroll
            for (int r = 0; r < 4; ++r) {
                float v = acc[i][j][r] + bv[r];
                pk[r] = (bf16)(isQ ? v * QSCALE : v);
            }
            *reinterpret_cast<bf16x4*>(
                reinterpret_cast<char*>(eb) + srt * 128 +
                (((j * 16 + 4 * lhi) * 2) ^ ((srt & 7) << 4))) = pk;
        }
    }
    const int h = (colbase & 1023) >> 6;
    const int mrow = m0 + wm * 64;
    const int bb = mrow >> 11, s0 = mrow & 2047;
    const long bh = (long)bb * NH + h;

    if (which < 2) {
        bf16* Ob = isQ ? Qb : Kb;
#pragma unroll
        for (int it = 0; it < 8; ++it) {
            int rt = it * 8 + (lane >> 3);
            bf16x8 v = *reinterpret_cast<const bf16x8*>(
                reinterpret_cast<char*>(eb) + rt * 128 +
                (((lane & 7) * 16) ^ ((rt & 7) << 4)));
            int s = s0 + rt;
            *reinterpret_cast<bf16x8*>(&Ob[(bh * NS + s) * HD + (lane & 7) * 8]) = v;
        }
    } else {
        // V: straight gather-transpose, full-line [d][s] store
        const int pos0 = (lane & 7) * 8;
#pragma unroll
        for (int it = 0; it < 8; ++it) {
            int dt = it * 8 + (lane >> 3);
            bf16x8 v;
#pragma unroll
            for (int j = 0; j < 8; ++j) {
                int s = pos0 + j;   // source s-row in eb
                v[j] = *reinterpret_cast<const bf16*>(
                    reinterpret_cast<char*>(eb) + s * 128 +
                    ((dt * 2) ^ ((s & 7) << 4)));
            }
            *reinterpret_cast<bf16x8*>(&Vt[(bh * HD + dt) * NS + s0 + pos0]) = v;
        }
    }
}

// ======== out-GEMM, 128x128, 2-phase + counted vmcnt, f32 full-line out ======
__global__ __launch_bounds__(256, 2) void k_gemmO(
    const bf16* __restrict__ A, const bf16* __restrict__ Bt,
    const float* __restrict__ bias, float* __restrict__ O, int Kd)
{
    constexpr int BM = 128, BN = 128, BK = 64;
    __shared__ __align__(16) bf16 As[2][BM * BK];
    __shared__ __align__(16) bf16 Bs[2][BN * BK];

    const int t = threadIdx.x;
    const int wid = t >> 6, lane = t & 63;
    const int wm = wid >> 1, wn = wid & 1;
    const int m0 = blockIdx.y * BM, n0 = blockIdx.x * BN;
    const int lrow = lane & 15, lhi = lane >> 4;

    const int srow0 = wid * 32 + (lane >> 3);
    const int scol = ((lane & 7) ^ (lane >> 3)) * 8;
    const bf16* ag = A + (long)(m0 + srow0) * Kd + scol;
    const bf16* bg = Bt + (long)(n0 + srow0) * Kd + scol;

    auto STAGE = [&](int buf_, int k0_) {
#pragma unroll
        for (int c = 0; c < 4; ++c) {
            GL16(ag + (long)(c * 8) * Kd + k0_, &As[buf_][(wid * 32 + c * 8) * BK]);
            GL16(bg + (long)(c * 8) * Kd + k0_, &Bs[buf_][(wid * 32 + c * 8) * BK]);
        }
    };

    f32x4 acc[4][4] = {};
    const int nt = Kd >> 6;
    const int swzr = (lrow & 7) << 4;
    int co[2];
#pragma unroll
    for (int kk = 0; kk < 2; ++kk)
        co[kk] = ((kk * 64 + lhi * 16) ^ swzr) >> 1;

    STAGE(0, 0);
    int cur = 0;
    for (int tix = 0; tix < nt; ++tix) {
        if (tix + 1 < nt) {
            STAGE(cur ^ 1, (tix + 1) * BK);
            asm volatile("s_waitcnt vmcnt(8)" ::: "memory");
        } else {
            asm volatile("s_waitcnt vmcnt(0)" ::: "memory");
        }
        __builtin_amdgcn_s_barrier();
        __builtin_amdgcn_sched_barrier(0);

        bf16x8 af[2][4], bfr[2][4];
#pragma unroll
        for (int kk = 0; kk < 2; ++kk)
#pragma unroll
            for (int i = 0; i < 4; ++i) {
                af[kk][i]  = *reinterpret_cast<const bf16x8*>(
                    &As[cur][(wm * 64 + i * 16 + lrow) * BK + co[kk]]);
                bfr[kk][i] = *reinterpret_cast<const bf16x8*>(
                    &Bs[cur][(wn * 64 + i * 16 + lrow) * BK + co[kk]]);
            }
        __builtin_amdgcn_s_setprio(1);
#pragma unroll
        for (int kk = 0; kk < 2; ++kk)
#pragma unroll
            for (int i = 0; i < 4; ++i)
#pragma unroll
                for (int j = 0; j < 4; ++j)
                    acc[i][j] = __builtin_amdgcn_mfma_f32_16x16x32_bf16(
                        bfr[kk][j], af[kk][i], acc[i][j], 0, 0, 0);
        __builtin_amdgcn_s_setprio(0);
        __builtin_amdgcn_s_barrier();
        cur ^= 1;
    }

    const int colbase = n0 + wn * 64;
    float* ef = (float*)As + wid * 2048;   // wave-private 32x64 f32 (8 KB)
#pragma unroll
    for (int half = 0; half < 2; ++half) {
#pragma unroll
        for (int i2 = 0; i2 < 2; ++i2) {
            int i = half * 2 + i2;
            int srt = i2 * 16 + lrow;
#pragma unroll
            for (int j = 0; j < 4; ++j) {
                f32x4 bv = *reinterpret_cast<const f32x4*>(
                    &bias[colbase + j * 16 + 4 * lhi]);
                f32x4 v = acc[i][j] + bv;
                *reinterpret_cast<f32x4*>(
                    reinterpret_cast<char*>(ef) + srt * 256 +
                    (((j * 16 + 4 * lhi) * 4) ^ ((srt & 7) << 4))) = v;
            }
        }
#pragma unroll
        for (int it = 0; it < 8; ++it) {
            int rt = it * 4 + (lane >> 4);
            f32x4 v = *reinterpret_cast<const f32x4*>(
                reinterpret_cast<char*>(ef) + rt * 256 +
                (((lane & 15) * 16) ^ ((rt & 7) << 4)));
            int row = m0 + wm * 64 + half * 32 + rt;
            *reinterpret_cast<f32x4*>(
                &O[(long)row * 1024 + colbase + (lane & 15) * 4]) = v;
        }
        asm volatile("" ::: "memory");   // half0 reads before half1 writes
    }
}

// ---------------- flash attention v13: 32x32 datapath + ones-MFMA lsum -------
// 8 waves, 256 q/block, 32 q/wave, KB=64 (r18's best-attn v11 base).
// QK swapped via mfma_32x32x16; P->PV B-frag via 2 permlane32_swap per chunk;
// PV swapped. NEW: softmax denominator l(q) accumulated by a ones-A MFMA
// (every lacc register = full l) -- removes 32 serial VALU adds/tile and the
// final cross-half shuffle. LDS = K/V dbuf 32 KB. Counted vmcnt(2) staging.
__global__ __launch_bounds__(512, 4) void k_attn(
    const bf16* __restrict__ Qb, const bf16* __restrict__ Kb,
    const bf16* __restrict__ Vt, bf16* __restrict__ Ao)
{
    constexpr int KB = 64;
    constexpr int NT = NS / KB;   // 32 tiles
    __shared__ __align__(16) bf16 Ks[2][KB * HD];   // 16 KB, row=key, swizzled
    __shared__ __align__(16) bf16 Vs[2][HD * KB];   // 16 KB, row=d,   swizzled

    const int t = threadIdx.x;
    const int wid = t >> 6, lane = t & 63;
    const int l31 = lane & 31, lh = lane >> 5;      // 32-lane row, half-select

    // bijective XCD swizzle: 512 blocks, 8 XCDs, 64 contiguous per XCD
    const int flat = blockIdx.y * gridDim.x + blockIdx.x;
    const int n = (flat & 7) * 64 + (flat >> 3);
    const int bh = n >> 3;
    const int qw = (n & 7) * 256 + wid * 32;   // wave's 32 q rows

    const bf16* Qg = Qb + ((long)bh * NS + qw) * HD;
    const bf16* Kg = Kb + (long)bh * NS * HD;
    const bf16* Vg = Vt + (long)bh * HD * NS;

    // Q fragments (B-operand, 32x32x16): col=q=l31, k(d) = kc*16 + 8*lh + {0..7}
    bf16x8 qf[4];
#pragma unroll
    for (int kc = 0; kc < 4; ++kc)
        qf[kc] = *reinterpret_cast<const bf16x8*>(
            Qg + (long)l31 * HD + kc * 16 + 8 * lh);

    // ones fragment (A-operand) for the denominator MFMA
    bf16x8 ones;
#pragma unroll
    for (int i = 0; i < 8; ++i) ones[i] = (bf16)1.0f;

    f32x16 of0 = {}, of1 = {}, lacc = {};

    // staging: wave w covers K rows w*8..+8 and V rows w*8..+8
    const int gsr = lane >> 3;
    const int gsc = ((lane & 7) ^ gsr) * 8;
    const int rb = wid * 8;
    auto STAGE = [&](int buf, int kb) {
        GL16(Kg + (long)(kb + rb + gsr) * HD + gsc, &Ks[buf][rb * 64]);
        GL16(Vg + (long)(rb + gsr) * NS + kb + gsc, &Vs[buf][rb * 64]);
    };

    auto COMPUTE = [&](int b_) {
        // QK: st[kt] = sum_kc mfma32x32x16(K[kt][kc], qf[kc])
        f32x16 st0 = {}, st1 = {};
        __builtin_amdgcn_s_setprio(1);
#pragma unroll
        for (int kc = 0; kc < 4; ++kc) {
            const int cb = (kc * 32 + 16 * lh);
            const int r0 = l31, r1 = 32 + l31;
            bf16x8 k0 = *reinterpret_cast<const bf16x8*>(
                &Ks[b_][r0 * 64 + ((cb ^ ((r0 & 7) << 4)) >> 1)]);
            bf16x8 k1 = *reinterpret_cast<const bf16x8*>(
                &Ks[b_][r1 * 64 + ((cb ^ ((r1 & 7) << 4)) >> 1)]);
            st0 = __builtin_amdgcn_mfma_f32_32x32x16_bf16(k0, qf[kc], st0, 0, 0, 0);
            st1 = __builtin_amdgcn_mfma_f32_32x32x16_bf16(k1, qf[kc], st1, 0, 0, 0);
        }
        __builtin_amdgcn_s_setprio(0);

        // softmax in-register; pack per group g: keys 8g + 4*lh + {0..3}
        unsigned u0[4][2], u1[4][2];
#pragma unroll
        for (int g = 0; g < 4; ++g) {
            float a0 = __builtin_amdgcn_exp2f(st0[4 * g]);
            float a1 = __builtin_amdgcn_exp2f(st0[4 * g + 1]);
            float a2 = __builtin_amdgcn_exp2f(st0[4 * g + 2]);
            float a3 = __builtin_amdgcn_exp2f(st0[4 * g + 3]);
            u0[g][0] = pk2(a0, a1); u0[g][1] = pk2(a2, a3);
            float b0 = __builtin_amdgcn_exp2f(st1[4 * g]);
            float b1 = __builtin_amdgcn_exp2f(st1[4 * g + 1]);
            float b2 = __builtin_amdgcn_exp2f(st1[4 * g + 2]);
            float b3 = __builtin_amdgcn_exp2f(st1[4 * g + 3]);
            u1[g][0] = pk2(b0, b1); u1[g][1] = pk2(b2, b3);
        }

        // PV: for global key-chunk kc: B-frag via 2 permlane32_swap; 2 d-tiles
        // + ones-MFMA accumulates the denominator into lacc (all regs = l(q)).
        __builtin_amdgcn_s_setprio(1);
#pragma unroll
        for (int kc = 0; kc < 4; ++kc) {
            const unsigned (*uu)[2] = (kc < 2) ? u0 : u1;
            const int gl = 2 * (kc & 1), gh = gl + 1;
            u32x2 sA = __builtin_amdgcn_permlane32_swap(uu[gl][0], uu[gh][0], false, false);
            u32x2 sB = __builtin_amdgcn_permlane32_swap(uu[gl][1], uu[gh][1], false, false);
            union { unsigned u[4]; bf16x8 v; } pf;
            pf.u[0] = sA[0]; pf.u[1] = sB[0]; pf.u[2] = sA[1]; pf.u[3] = sB[1];
            const int cb = kc * 32 + 16 * lh;
#pragma unroll
            for (int dt = 0; dt < 2; ++dt) {
                const int row = dt * 32 + l31;
                bf16x8 vf = *reinterpret_cast<const bf16x8*>(
                    &Vs[b_][row * 64 + ((cb ^ ((row & 7) << 4)) >> 1)]);
                if (dt == 0)
                    of0 = __builtin_amdgcn_mfma_f32_32x32x16_bf16(vf, pf.v, of0, 0, 0, 0);
                else
                    of1 = __builtin_amdgcn_mfma_f32_32x32x16_bf16(vf, pf.v, of1, 0, 0, 0);
            }
            lacc = __builtin_amdgcn_mfma_f32_32x32x16_bf16(ones, pf.v, lacc, 0, 0, 0);
        }
        __builtin_amdgcn_s_setprio(0);
    };

    STAGE(0, 0);
    int cur = 0;
    for (int it = 0; it < NT; ++it) {
        if (it + 1 < NT) {
            STAGE(cur ^ 1, (it + 1) * KB);
            asm volatile("s_waitcnt vmcnt(2)" ::: "memory");  // cur's 2 landed
        } else {
            asm volatile("s_waitcnt vmcnt(0)" ::: "memory");
        }
        __builtin_amdgcn_s_barrier();
        __builtin_amdgcn_sched_barrier(0);
        COMPUTE(cur);
        __builtin_amdgcn_s_barrier();   // reads of cur done -> overwrite ok
        cur ^= 1;
    }

    // every lacc register already holds the full l(q = lane&31)
    const float inv = 1.0f / lacc[0];

    // epilogue: wave-private 32(q) x 64(d) transpose; waves 0-3 in Ks, 4-7 in Vs
    bf16* eb = (wid < 4) ? ((bf16*)Ks + wid * 2048) : ((bf16*)Vs + (wid - 4) * 2048);
    const int qrow = l31;
#pragma unroll
    for (int dt = 0; dt < 2; ++dt)
#pragma unroll
        for (int g = 0; g < 4; ++g) {
            bf16x4 pk;
#pragma unroll
            for (int r = 0; r < 4; ++r) {
                float v = (dt == 0) ? of0[4 * g + r] : of1[4 * g + r];
                pk[r] = (bf16)(v * inv);
            }
            int d = dt * 32 + 8 * g + 4 * lh;
            *reinterpret_cast<bf16x4*>(
                reinterpret_cast<char*>(eb) + qrow * 128 +
                ((d * 2) ^ ((qrow & 7) << 4))) = pk;
        }
    const int bb = bh >> 4, h = bh & 15;
#pragma unroll
    for (int it = 0; it < 4; ++it) {
        int rt = it * 8 + (lane >> 3);
        bf16x8 v = *reinterpret_cast<const bf16x8*>(
            reinterpret_cast<char*>(eb) + rt * 128 +
            (((lane & 7) * 16) ^ ((rt & 7) << 4)));
        int s = qw + rt;
        *reinterpret_cast<bf16x8*>(
            &Ao[((long)bb * NS + s) * ND + h * HD + (lane & 7) * 8]) = v;
    }
}

// ---------------- launch ----------------
extern "C" void kernel_launch(void* const* d_in, const int* in_sizes, int n_in,
                              void* d_out, int out_size, void* d_ws, size_t ws_size,
                              hipStream_t stream) {
    const float* x    = (const float*)d_in[0];
    const float* Wqkv = (const float*)d_in[1];
    const float* bqkv = (const float*)d_in[2];
    const float* Wout = (const float*)d_in[3];
    const float* bout = (const float*)d_in[4];
    float* out = (float*)d_out;

    char* ws = (char*)d_ws;
    bf16* Xb  = (bf16*)(ws);                         // 16.78 MB
    bf16* Wqt = (bf16*)(ws + 16777216);              //  6.29 MB
    bf16* Wot = (bf16*)(ws + 23068672);              //  2.10 MB
    bf16* Qb  = (bf16*)(ws + 25165824);              // 16.78 MB
    bf16* Kb  = (bf16*)(ws + 41943040);              // 16.78 MB
    bf16* Vt  = (bf16*)(ws + 58720256);              // 16.78 MB
    bf16* Ab  = (bf16*)(ws + 75497472);              // 16.78 MB  (total ~92 MB)

    k_conv<<<dim3(8192), dim3(256), 0, stream>>>(x, Xb, NB * NS * ND);
    k_transconv<<<dim3(96, 16), dim3(32, 8), 0, stream>>>(Wqkv, Wqt, ND, 3 * ND);
    k_transconv<<<dim3(32, 16), dim3(32, 8), 0, stream>>>(Wout, Wot, ND, ND);

    // merged QKV producer: 1536 blocks = 3 exact generations at 2/CU
    k_gemmQKV<<<dim3(24, 64), dim3(256), 0, stream>>>(
        Xb, Wqt, bqkv, Qb, Kb, Vt, ND);

    k_attn<<<dim3(8, 64), dim3(512), 0, stream>>>(Qb, Kb, Vt, Ab);

    k_gemmO<<<dim3(8, 64), dim3(256), 0, stream>>>(
        Ab, Wot, bout, out, ND);
}